// Round 4
// baseline (1605.970 us; speedup 1.0000x reference)
//
#include <hip/hip_runtime.h>
#include <hip/hip_bf16.h>

#define NN 32768
#define EE 262144
#define FD 128
#define NL 64
#define MROW 16     // nodes per block — 2048 blocks, 8/CU, 32 waves/CU
#define SROW 132    // LDS row stride (ushorts)
#define NBLK (NN / MROW)        // 2048 == exact co-residency at 8 blocks/CU
#define BARGRP 64               // barrier groups (also # of leader blocks)
#define GRPSZ (NBLK / BARGRP)   // 32 blocks per group

// bar layout in 64-int (256 B) lines:
//   line g       (g=0..63)   : group arrive counter   bar[g*64]
//   line 64                  : root arrive counter    bar[64*64]
//   line 65                  : root release epoch     bar[65*64]
//   line 66+g    (g=0..63)   : group release epoch    bar[(66+g)*64]
#define BAR_INTS (130 * 64)

typedef short v8s __attribute__((ext_vector_type(8)));
typedef float v4f __attribute__((ext_vector_type(4)));

__device__ __forceinline__ unsigned short f2bf(float x) {
    unsigned u = __builtin_bit_cast(unsigned, x);
    u += 0x7fffu + ((u >> 16) & 1u);
    return (unsigned short)(u >> 16);
}
__device__ __forceinline__ float bf2f(unsigned short h) {
    unsigned u = ((unsigned)h) << 16;
    return __builtin_bit_cast(float, u);
}
// accumulate 8 bf16 (packed in v8s) into acc[8]
__device__ __forceinline__ void acc8_bf16(float* acc, v8s r) {
    const int* d = (const int*)&r;
#pragma unroll
    for (int k = 0; k < 4; k++) {
        unsigned u = (unsigned)d[k];
        acc[2 * k]     += __builtin_bit_cast(float, u << 16);
        acc[2 * k + 1] += __builtin_bit_cast(float, u & 0xffff0000u);
    }
}

// ---- coherent (cross-XCD) 16B accesses: bypass L1/L2, served at the
// coherent point (MALL). No cache-maintenance fences needed (R2 lesson:
// threadfence = wbL2+inv per block per layer = 8x disaster).
__device__ __forceinline__ v8s load16_sc(const unsigned short* p) {
    v8s r;
    asm volatile("global_load_dwordx4 %0, %1, off sc0 sc1"
                 : "=&v"(r) : "v"(p) : "memory");
    return r;
}
__device__ __forceinline__ void store16_sc(unsigned short* p, v8s v) {
    asm volatile("global_store_dwordx4 %0, %1, off sc0 sc1"
                 :: "v"(p), "v"(v) : "memory");
}
__device__ __forceinline__ void wait_vm0() {
    asm volatile("s_waitcnt vmcnt(0)" ::: "memory");
    __builtin_amdgcn_sched_barrier(0);
}
// counted wait: batch in flight stays in flight (R4: the pipelining fix).
__device__ __forceinline__ void wait_vm4() {
    asm volatile("s_waitcnt vmcnt(4)" ::: "memory");
    __builtin_amdgcn_sched_barrier(0);
}

// ---------- setup ----------
__global__ __launch_bounds__(256) void k_deg(const int* __restrict__ dst,
                                             int* __restrict__ cnt) {
    int e = blockIdx.x * 256 + threadIdx.x;
    if (e < EE) atomicAdd(&cnt[dst[e]], 1);
}

__global__ __launch_bounds__(256) void k_dinv(const int* __restrict__ cnt,
                                              float* __restrict__ dinv) {
    int i = blockIdx.x * 256 + threadIdx.x;
    if (i < NN) dinv[i] = rsqrtf((float)cnt[i] + 1.0f);
}

// hierarchical scan
__global__ __launch_bounds__(256) void k_scanA(const int* __restrict__ cnt,
                                               int* __restrict__ bsum) {
    __shared__ int ws[4];
    int tid = threadIdx.x;
    int v = cnt[blockIdx.x * 256 + tid];
    int x = v;
#pragma unroll
    for (int off = 1; off < 64; off <<= 1) x += __shfl_xor(x, off);
    if ((tid & 63) == 0) ws[tid >> 6] = x;
    __syncthreads();
    if (tid == 0) bsum[blockIdx.x] = ws[0] + ws[1] + ws[2] + ws[3];
}
__global__ __launch_bounds__(128) void k_scanB(const int* __restrict__ bsum,
                                               int* __restrict__ boff,
                                               int* __restrict__ offs) {
    __shared__ int s0;
    int tid = threadIdx.x;
    int v = bsum[tid];
    int lane = tid & 63, w = tid >> 6;
    int x = v;
#pragma unroll
    for (int off = 1; off < 64; off <<= 1) {
        int y = __shfl_up(x, off);
        if (lane >= off) x += y;
    }
    if (tid == 63) s0 = x;
    __syncthreads();
    int excl = x - v + (w ? s0 : 0);
    boff[tid] = excl;
    if (tid == 127) offs[NN] = excl + v;
}
__global__ __launch_bounds__(256) void k_scanC(const int* __restrict__ cnt,
                                               const int* __restrict__ boff,
                                               int* __restrict__ offs) {
    __shared__ int ws[4];
    int tid = threadIdx.x;
    int i = blockIdx.x * 256 + tid;
    int v = cnt[i];
    int lane = tid & 63, w = tid >> 6;
    int x = v;
#pragma unroll
    for (int off = 1; off < 64; off <<= 1) {
        int y = __shfl_up(x, off);
        if (lane >= off) x += y;
    }
    if (lane == 63) ws[w] = x;
    __syncthreads();
    int wexcl = 0;
#pragma unroll
    for (int k = 0; k < 4; k++) if (k < w) wexcl += ws[k];
    offs[i] = boff[blockIdx.x] + wexcl + x - v;
}

__global__ __launch_bounds__(256) void k_fill(const int* __restrict__ src,
                                              const int* __restrict__ dst,
                                              const int* __restrict__ offs,
                                              int* __restrict__ cursor,
                                              int* __restrict__ col) {
    int e = blockIdx.x * 256 + threadIdx.x;
    if (e >= EE) return;
    int s = src[e], d = dst[e];
    int slot = atomicAdd(&cursor[d], 1);
    col[offs[d] + slot] = s;
}

// g0 = bf16(dinv[node] * x)
__global__ __launch_bounds__(256) void k_xcast(const float* __restrict__ x,
                                               const float* __restrict__ dinv,
                                               unsigned short* __restrict__ g) {
    int i = blockIdx.x * 256 + threadIdx.x;
    float di = dinv[(i * 8) >> 7];
    float4 a = *(const float4*)(x + (size_t)i * 8);
    float4 b = *(const float4*)(x + (size_t)i * 8 + 4);
    v8s o;
    o[0] = (short)f2bf(di * a.x); o[1] = (short)f2bf(di * a.y);
    o[2] = (short)f2bf(di * a.z); o[3] = (short)f2bf(di * a.w);
    o[4] = (short)f2bf(di * b.x); o[5] = (short)f2bf(di * b.y);
    o[6] = (short)f2bf(di * b.z); o[7] = (short)f2bf(di * b.w);
    *(v8s*)(g + (size_t)i * 8) = o;
}

// ---------- weight cast: fp32 W -> bf16 in MFMA B-fragment order ----------
__global__ __launch_bounds__(256) void k_wcast(const float* __restrict__ W,
                                               unsigned short* __restrict__ Whi) {
    int t = blockIdx.x * 256 + threadIdx.x;
    int l = t >> 11;
    int rem = t & 2047;
    int ks = rem >> 9;
    int rem2 = rem & 511;
    int nt = rem2 >> 6;
    int L = rem2 & 63;
    const float* Wl = W + (size_t)l * FD * FD;
    int kbase = ks * 32 + ((L >> 4) << 3);
    int n = nt * 16 + (L & 15);
    v8s hv;
#pragma unroll
    for (int j = 0; j < 8; j++)
        hv[j] = (short)f2bf(Wl[(size_t)(kbase + j) * FD + n]);
    *(v8s*)(Whi + (size_t)t * 8) = hv;
}

// ---------- fused 64-layer network, one persistent kernel ----------
// v4: software-pipelined gather (width 4, depth 2, counted vmcnt(4) —
// never vmcnt(0) in the loop). R3 drained vmcnt(0) per batch -> 24.5%
// VALUBusy, 75% idle. FIFO vmcnt retirement makes vmcnt(4) safe even if
// the compiler interleaves its own loads (they're drained conservatively,
// never prematurely).
__global__ __launch_bounds__(256, 8) void k_net(
        unsigned short* __restrict__ h0,
        unsigned short* __restrict__ h1,
        const int* __restrict__ offs,
        const int* __restrict__ col,
        const unsigned short* __restrict__ Whi,
        const float* __restrict__ dinv,
        const float* __restrict__ biases,
        const float* __restrict__ x,
        const float* __restrict__ cw,
        const float* __restrict__ cb,
        float* __restrict__ out,
        int* __restrict__ bar) {
    __shared__ unsigned short sA[MROW * SROW];
    __shared__ float sDinv[MROW];
    int tid = threadIdx.x;
    int lane = tid & 63;
    int w = tid >> 6;
    int row0 = blockIdx.x * MROW;
    int fg = lane >> 4;        // node subgroup 0..3
    int fl = lane & 15;        // feature chunk (8 feats = 16B)
    int grp = blockIdx.x & (BARGRP - 1);
    bool leader = (blockIdx.x < BARGRP);

    if (tid < MROW) sDinv[tid] = dinv[row0 + tid];

    // ---- layer-invariant prologue ----
    int nbase = row0 + w * 4;
    int4 ov = *(const int4*)(offs + nbase);
    int o4 = offs[nbase + 4];
    int B0 = ov.x;
    int Etot = o4 - B0;
    int node = nbase + fg;
    float dself = dinv[node];
    bool fast = (Etot <= 64);
    int cwin = 0, sg = 0, eg = 0, m = 0;
    if (fast) {
        cwin = (lane < Etot) ? col[B0 + lane] : 0;   // col window held 64 layers
        sg = ((fg == 0) ? ov.x : (fg == 1) ? ov.y : (fg == 2) ? ov.z : ov.w) - B0;
        eg = ((fg == 0) ? ov.y : (fg == 1) ? ov.z : (fg == 2) ? ov.w : o4) - B0;
        int len = eg - sg;
        m = max(len, __shfl_xor(len, 16));
        m = max(m, __shfl_xor(m, 32));      // wave-uniform max deg (4 groups)
    }

    for (int l = 0; l < NL; ++l) {
        const unsigned short* gin  = (l & 1) ? h0 : h1;  // l=0 reads h1 (g0)
        unsigned short* gout       = (l & 1) ? h1 : h0;
        const unsigned short* gf = gin + fl * 8;
        const unsigned short* Wl = Whi + (size_t)l * FD * FD;

        // ---- phase 1: gather + aggregate (pipelined coherent loads) ----
        if (fast) {
            float acc[8];
#pragma unroll
            for (int k = 0; k < 8; k++) acc[k] = 0.f;
            // self loop: for l>0 our own row is still in sA from the epilogue
            v8s selfv;
            if (l == 0) {
                selfv = load16_sc(gf + (size_t)node * FD);
                wait_vm0();
            } else {
                selfv = *(const v8s*)&sA[(w * 4 + fg) * SROW + fl * 8];
            }
            acc8_bf16(acc, selfv);

            // width-4 / depth-2 pipelined gather
            v8s A0, A1, A2, A3, B0r, B1r, B2r, B3r;
            auto issue4 = [&](int t, v8s& x0, v8s& x1, v8s& x2, v8s& x3) {
                int i0 = sg + t, i1 = sg + t + 1, i2 = sg + t + 2, i3 = sg + t + 3;
                int s0 = __shfl(cwin, i0 & 63);
                int s1 = __shfl(cwin, i1 & 63);
                int s2 = __shfl(cwin, i2 & 63);
                int s3 = __shfl(cwin, i3 & 63);
                const unsigned short* a0 = (i0 < eg) ? (gf + (size_t)s0 * FD) : gf;
                const unsigned short* a1 = (i1 < eg) ? (gf + (size_t)s1 * FD) : gf;
                const unsigned short* a2 = (i2 < eg) ? (gf + (size_t)s2 * FD) : gf;
                const unsigned short* a3 = (i3 < eg) ? (gf + (size_t)s3 * FD) : gf;
                x0 = load16_sc(a0);
                x1 = load16_sc(a1);
                x2 = load16_sc(a2);
                x3 = load16_sc(a3);
            };
            auto acc4 = [&](int t, v8s x0, v8s x1, v8s x2, v8s x3) {
                if (sg + t     < eg) acc8_bf16(acc, x0);
                if (sg + t + 1 < eg) acc8_bf16(acc, x1);
                if (sg + t + 2 < eg) acc8_bf16(acc, x2);
                if (sg + t + 3 < eg) acc8_bf16(acc, x3);
            };
            if (m > 0) {
                issue4(0, A0, A1, A2, A3);
                int t = 0;
                while (true) {
                    bool more = (t + 4 < m);          // wave-uniform
                    if (more) issue4(t + 4, B0r, B1r, B2r, B3r);
                    if (more) wait_vm4(); else wait_vm0();
                    acc4(t, A0, A1, A2, A3);
                    t += 4;
                    if (!more) break;
                    bool more2 = (t + 4 < m);
                    if (more2) issue4(t + 4, A0, A1, A2, A3);
                    if (more2) wait_vm4(); else wait_vm0();
                    acc4(t, B0r, B1r, B2r, B3r);
                    t += 4;
                    if (!more2) break;
                }
            }
            unsigned pk[4];
#pragma unroll
            for (int k = 0; k < 4; k++) {
                pk[k] = (unsigned)f2bf(dself * acc[2 * k]) |
                        ((unsigned)f2bf(dself * acc[2 * k + 1]) << 16);
            }
            *(v8s*)&sA[(w * 4 + fg) * SROW + fl * 8] = *(v8s*)pk;
        } else {
            // rare path: per-node col loads, any degree
            for (int r = 0; r < 4; r++) {
                int nloc = w * 4 + r;
                int nd = row0 + nloc;
                float acc[8];
#pragma unroll
                for (int k = 0; k < 8; k++) acc[k] = 0.f;
                int b = offs[nd], e = offs[nd + 1];
                int deg = e - b;
                for (int base = 0; base < deg; base += 64) {
                    int n = min(deg - base, 64);
                    int c = (lane < n) ? col[b + base + lane] : 0;
                    for (int j = 0; j < n; j += 8) {
                        int e0 = j + fg, e1 = j + 4 + fg;
                        int s0 = __shfl(c, e0 & 63);
                        int s1 = __shfl(c, e1 & 63);
                        bool p0 = e0 < n, p1 = e1 < n;
                        const unsigned short* a0 = p0 ? (gf + (size_t)s0 * FD) : gf;
                        const unsigned short* a1 = p1 ? (gf + (size_t)s1 * FD) : gf;
                        v8s r0 = load16_sc(a0);
                        v8s r1 = load16_sc(a1);
                        wait_vm0();
                        if (p0) acc8_bf16(acc, r0);
                        if (p1) acc8_bf16(acc, r1);
                    }
                }
#pragma unroll
                for (int k = 0; k < 8; k++) {
                    acc[k] += __shfl_xor(acc[k], 16);
                    acc[k] += __shfl_xor(acc[k], 32);
                }
                v8s sv;
                if (l == 0) {
                    sv = load16_sc(gf + (size_t)nd * FD);
                    wait_vm0();
                } else {
                    sv = *(const v8s*)&sA[nloc * SROW + fl * 8];
                }
                acc8_bf16(acc, sv);
                if (fg == 0) {
                    float di = dinv[nd];
                    unsigned pk[4];
#pragma unroll
                    for (int k = 0; k < 4; k++) {
                        pk[k] = (unsigned)f2bf(di * acc[2 * k]) |
                                ((unsigned)f2bf(di * acc[2 * k + 1]) << 16);
                    }
                    *(v8s*)&sA[nloc * SROW + fl * 8] = *(v8s*)pk;
                }
            }
        }
        __syncthreads();

        // ---- phase 2: 16x128 @ 128x128 MFMA (A from LDS, W bf16 from L2) ----
        v4f a0 = (v4f){0.f, 0.f, 0.f, 0.f};
        v4f a1 = (v4f){0.f, 0.f, 0.f, 0.f};
#pragma unroll
        for (int ks = 0; ks < 4; ks++) {
            v8s ah = *(const v8s*)&sA[(lane & 15) * SROW + ks * 32 + ((lane >> 4) << 3)];
            size_t bo0 = ((size_t)(ks * 8 + w * 2) * 64 + lane) * 8;
            size_t bo1 = ((size_t)(ks * 8 + w * 2 + 1) * 64 + lane) * 8;
            v8s bh0 = *(const v8s*)(Wl + bo0);
            v8s bh1 = *(const v8s*)(Wl + bo1);
            a0 = __builtin_amdgcn_mfma_f32_16x16x32_bf16(ah, bh0, a0, 0, 0, 0);
            a1 = __builtin_amdgcn_mfma_f32_16x16x32_bf16(ah, bh1, a1, 0, 0, 0);
        }
        __syncthreads();  // before reusing sA

        // ---- epilogue: bias + relu (+ dinv unless last), into sA ----
        bool last = (l == NL - 1);
        float bb0 = biases[(size_t)l * FD + w * 32 + (lane & 15)];
        float bb1 = biases[(size_t)l * FD + w * 32 + 16 + (lane & 15)];
#pragma unroll
        for (int nt = 0; nt < 2; nt++) {
            int col_l = w * 32 + nt * 16 + (lane & 15);
            float bb = nt ? bb1 : bb0;
            v4f a = nt ? a1 : a0;
#pragma unroll
            for (int rg = 0; rg < 4; rg++) {
                int row_l = ((lane >> 4) << 2) + rg;
                float v = fmaxf(a[rg] + bb, 0.f);
                if (!last) v *= sDinv[row_l];
                sA[row_l * SROW + col_l] = f2bf(v);
            }
        }
        __syncthreads();

        if (!last) {
            // store h for other blocks' gathers — write-through coherent
            int orow = tid >> 4;
            int ocol = (tid & 15) * 8;
            v8s hv = *(const v8s*)&sA[orow * SROW + ocol];
            store16_sc(gout + (size_t)(row0 + orow) * FD + ocol, hv);
            wait_vm0();        // store ack'd at coherent point before arrive

            // ---- device-wide barrier, hierarchical, no cache maintenance ----
            __syncthreads();
            if (tid == 0) {
                int a = atomicAdd(&bar[grp * 64], 1);            // group arrive
                if (a == GRPSZ * (l + 1) - 1) {
                    int r = atomicAdd(&bar[64 * 64], 1);         // root arrive
                    if (r == BARGRP * (l + 1) - 1) {
                        __hip_atomic_store(&bar[65 * 64], l + 1,
                                           __ATOMIC_RELAXED, __HIP_MEMORY_SCOPE_AGENT);
                    }
                }
                if (leader) {
                    while (__hip_atomic_load(&bar[65 * 64], __ATOMIC_RELAXED,
                                             __HIP_MEMORY_SCOPE_AGENT) < l + 1)
                        __builtin_amdgcn_s_sleep(4);
                    __hip_atomic_store(&bar[(66 + grp) * 64], l + 1,
                                       __ATOMIC_RELAXED, __HIP_MEMORY_SCOPE_AGENT);
                } else {
                    while (__hip_atomic_load(&bar[(66 + grp) * 64], __ATOMIC_RELAXED,
                                             __HIP_MEMORY_SCOPE_AGENT) < l + 1)
                        __builtin_amdgcn_s_sleep(16);
                }
                asm volatile("" ::: "memory");
            }
            __syncthreads();
        } else {
            // ---- fused classifier: out = (h + x) @ cw + cb, h in sA ----
            int row = tid >> 4;          // 0..15
            int t = tid & 15;            // feature octet
            int nd = row0 + row;
            const unsigned short* hr = &sA[row * SROW + t * 8];
            const float* xr = x + (size_t)nd * FD + t * 8;
            float xv[8];
            *(float4*)&xv[0] = *(const float4*)xr;
            *(float4*)&xv[4] = *(const float4*)(xr + 4);
            float p0 = 0.f, p1 = 0.f, p2 = 0.f, p3 = 0.f;
#pragma unroll
            for (int j = 0; j < 8; j++) {
                float s = bf2f(hr[j]) + xv[j];
                float4 wv = *(const float4*)(cw + (size_t)(t * 8 + j) * 4);
                p0 += s * wv.x; p1 += s * wv.y; p2 += s * wv.z; p3 += s * wv.w;
            }
#pragma unroll
            for (int off = 1; off < 16; off <<= 1) {
                p0 += __shfl_xor(p0, off);
                p1 += __shfl_xor(p1, off);
                p2 += __shfl_xor(p2, off);
                p3 += __shfl_xor(p3, off);
            }
            if (t == 0) {
                float4 r = make_float4(p0 + cb[0], p1 + cb[1], p2 + cb[2], p3 + cb[3]);
                *(float4*)(out + (size_t)nd * 4) = r;
            }
        }
    }
}

extern "C" void kernel_launch(void* const* d_in, const int* in_sizes, int n_in,
                              void* d_out, int out_size, void* d_ws, size_t ws_size,
                              hipStream_t stream) {
    const float* x       = (const float*)d_in[0];
    const int* ei        = (const int*)d_in[1];       // [2][EE], int32
    const float* weights = (const float*)d_in[2];
    const float* biases  = (const float*)d_in[3];
    const float* cls_w   = (const float*)d_in[4];
    const float* cls_b   = (const float*)d_in[5];
    float* out = (float*)d_out;

    char* ws = (char*)d_ws;
    size_t off = 0;
    auto alloc = [&](size_t bytes) -> void* {
        off = (off + 255) & ~(size_t)255;
        void* p = ws + off;
        off += bytes;
        return p;
    };
    int*   cnt    = (int*)alloc((size_t)NN * 4);
    int*   cursor = (int*)alloc((size_t)NN * 4);
    float* dinv   = (float*)alloc((size_t)NN * 4);
    int*   offs   = (int*)alloc((size_t)(NN + 1) * 4);
    int*   bsum   = (int*)alloc((size_t)128 * 4);
    int*   boff   = (int*)alloc((size_t)128 * 4);
    int*   bar    = (int*)alloc((size_t)BAR_INTS * 4);
    int*   col    = (int*)alloc((size_t)EE * 4);
    unsigned short* Whi = (unsigned short*)alloc((size_t)NL * FD * FD * 2);
    unsigned short* h0  = (unsigned short*)alloc((size_t)NN * FD * 2);
    unsigned short* h1  = (unsigned short*)alloc((size_t)NN * FD * 2);

    const int* srcv = ei;
    const int* dstv = ei + EE;

    hipMemsetAsync(cnt, 0, (size_t)NN * 4, stream);
    hipMemsetAsync(cursor, 0, (size_t)NN * 4, stream);
    hipMemsetAsync(bar, 0, (size_t)BAR_INTS * 4, stream);
    k_deg<<<EE / 256, 256, 0, stream>>>(dstv, cnt);
    k_dinv<<<NN / 256, 256, 0, stream>>>(cnt, dinv);
    k_scanA<<<128, 256, 0, stream>>>(cnt, bsum);
    k_scanB<<<1, 128, 0, stream>>>(bsum, boff, offs);
    k_scanC<<<128, 256, 0, stream>>>(cnt, boff, offs);
    k_fill<<<EE / 256, 256, 0, stream>>>(srcv, dstv, offs, cursor, col);
    k_wcast<<<NL * 2048 / 256, 256, 0, stream>>>(weights, Whi);
    k_xcast<<<NN * FD / 2048, 256, 0, stream>>>(x, dinv, h1);  // g0 in h1

    // all 64 layers + classifier in ONE persistent kernel
    k_net<<<NBLK, 256, 0, stream>>>(h0, h1, offs, col, Whi, dinv, biases,
                                    x, cls_w, cls_b, out, bar);
}

// Round 5
// 1494.314 us; speedup vs baseline: 1.0747x; 1.0747x over previous
//
#include <hip/hip_runtime.h>
#include <hip/hip_bf16.h>

#define NN 32768
#define EE 262144
#define FD 128
#define NL 64
#define MROW 16     // nodes per block — 2048 blocks, 8/CU, 32 waves/CU
#define SROW 132    // LDS row stride (ushorts)
#define NBLK (NN / MROW)        // 2048 == exact co-residency at 8 blocks/CU
#define BARGRP 64               // barrier groups (also # of leader blocks)
#define GRPSZ (NBLK / BARGRP)   // 32 blocks per group

// bar layout in 64-int (256 B) lines:
//   line g       (g=0..63)   : group arrive counter   bar[g*64]
//   line 64                  : root arrive counter    bar[64*64]
//   line 65                  : root release epoch     bar[65*64]
//   line 66+g    (g=0..63)   : group release epoch    bar[(66+g)*64]
//   line 130+x   (x=0..7)    : per-XCD inv-election epoch
//   line 138+x   (x=0..7)    : per-XCD inv-done epoch
#define BAR_INTS (146 * 64)

typedef short v8s __attribute__((ext_vector_type(8)));
typedef float v4f __attribute__((ext_vector_type(4)));

__device__ __forceinline__ unsigned short f2bf(float x) {
    unsigned u = __builtin_bit_cast(unsigned, x);
    u += 0x7fffu + ((u >> 16) & 1u);
    return (unsigned short)(u >> 16);
}
__device__ __forceinline__ float bf2f(unsigned short h) {
    unsigned u = ((unsigned)h) << 16;
    return __builtin_bit_cast(float, u);
}
// accumulate 8 bf16 (packed in v8s) into acc[8]
__device__ __forceinline__ void acc8_bf16(float* acc, v8s r) {
    const int* d = (const int*)&r;
#pragma unroll
    for (int k = 0; k < 4; k++) {
        unsigned u = (unsigned)d[k];
        acc[2 * k]     += __builtin_bit_cast(float, u << 16);
        acc[2 * k + 1] += __builtin_bit_cast(float, u & 0xffff0000u);
    }
}

// L1-bypass, L2-CACHED load (sc0 only). h gathers must skip the per-CU L1
// (stale across layers) but may use the XCD L2 because we invalidate L2
// once per XCD per layer (elected buffer_inv sc1 below). This is the
// R5 fix: R3/R4's sc0+sc1 loads pushed every gather to the coherent
// fabric (~3 TB/s random ceiling -> 20 us/layer, unbeatable floor).
__device__ __forceinline__ v8s load16_l2(const unsigned short* p) {
    v8s r;
    asm volatile("global_load_dwordx4 %0, %1, off sc0"
                 : "=&v"(r) : "v"(p) : "memory");
    return r;
}
// coherent write-through store: h never dirty in L2 -> no wbl2 needed ever.
__device__ __forceinline__ void store16_sc(unsigned short* p, v8s v) {
    asm volatile("global_store_dwordx4 %0, %1, off sc0 sc1"
                 :: "v"(p), "v"(v) : "memory");
}
__device__ __forceinline__ void wait_vm0() {
    asm volatile("s_waitcnt vmcnt(0)" ::: "memory");
    __builtin_amdgcn_sched_barrier(0);
}

// ---------- setup ----------
__global__ __launch_bounds__(256) void k_deg(const int* __restrict__ dst,
                                             int* __restrict__ cnt) {
    int e = blockIdx.x * 256 + threadIdx.x;
    if (e < EE) atomicAdd(&cnt[dst[e]], 1);
}

__global__ __launch_bounds__(256) void k_dinv(const int* __restrict__ cnt,
                                              float* __restrict__ dinv) {
    int i = blockIdx.x * 256 + threadIdx.x;
    if (i < NN) dinv[i] = rsqrtf((float)cnt[i] + 1.0f);
}

// hierarchical scan
__global__ __launch_bounds__(256) void k_scanA(const int* __restrict__ cnt,
                                               int* __restrict__ bsum) {
    __shared__ int ws[4];
    int tid = threadIdx.x;
    int v = cnt[blockIdx.x * 256 + tid];
    int x = v;
#pragma unroll
    for (int off = 1; off < 64; off <<= 1) x += __shfl_xor(x, off);
    if ((tid & 63) == 0) ws[tid >> 6] = x;
    __syncthreads();
    if (tid == 0) bsum[blockIdx.x] = ws[0] + ws[1] + ws[2] + ws[3];
}
__global__ __launch_bounds__(128) void k_scanB(const int* __restrict__ bsum,
                                               int* __restrict__ boff,
                                               int* __restrict__ offs) {
    __shared__ int s0;
    int tid = threadIdx.x;
    int v = bsum[tid];
    int lane = tid & 63, w = tid >> 6;
    int x = v;
#pragma unroll
    for (int off = 1; off < 64; off <<= 1) {
        int y = __shfl_up(x, off);
        if (lane >= off) x += y;
    }
    if (tid == 63) s0 = x;
    __syncthreads();
    int excl = x - v + (w ? s0 : 0);
    boff[tid] = excl;
    if (tid == 127) offs[NN] = excl + v;
}
__global__ __launch_bounds__(256) void k_scanC(const int* __restrict__ cnt,
                                               const int* __restrict__ boff,
                                               int* __restrict__ offs) {
    __shared__ int ws[4];
    int tid = threadIdx.x;
    int i = blockIdx.x * 256 + tid;
    int v = cnt[i];
    int lane = tid & 63, w = tid >> 6;
    int x = v;
#pragma unroll
    for (int off = 1; off < 64; off <<= 1) {
        int y = __shfl_up(x, off);
        if (lane >= off) x += y;
    }
    if (lane == 63) ws[w] = x;
    __syncthreads();
    int wexcl = 0;
#pragma unroll
    for (int k = 0; k < 4; k++) if (k < w) wexcl += ws[k];
    offs[i] = boff[blockIdx.x] + wexcl + x - v;
}

__global__ __launch_bounds__(256) void k_fill(const int* __restrict__ src,
                                              const int* __restrict__ dst,
                                              const int* __restrict__ offs,
                                              int* __restrict__ cursor,
                                              int* __restrict__ col) {
    int e = blockIdx.x * 256 + threadIdx.x;
    if (e >= EE) return;
    int s = src[e], d = dst[e];
    int slot = atomicAdd(&cursor[d], 1);
    col[offs[d] + slot] = s;
}

// g0 = bf16(dinv[node] * x)
__global__ __launch_bounds__(256) void k_xcast(const float* __restrict__ x,
                                               const float* __restrict__ dinv,
                                               unsigned short* __restrict__ g) {
    int i = blockIdx.x * 256 + threadIdx.x;
    float di = dinv[(i * 8) >> 7];
    float4 a = *(const float4*)(x + (size_t)i * 8);
    float4 b = *(const float4*)(x + (size_t)i * 8 + 4);
    v8s o;
    o[0] = (short)f2bf(di * a.x); o[1] = (short)f2bf(di * a.y);
    o[2] = (short)f2bf(di * a.z); o[3] = (short)f2bf(di * a.w);
    o[4] = (short)f2bf(di * b.x); o[5] = (short)f2bf(di * b.y);
    o[6] = (short)f2bf(di * b.z); o[7] = (short)f2bf(di * b.w);
    *(v8s*)(g + (size_t)i * 8) = o;
}

// ---------- weight cast: fp32 W -> bf16 in MFMA B-fragment order ----------
__global__ __launch_bounds__(256) void k_wcast(const float* __restrict__ W,
                                               unsigned short* __restrict__ Whi) {
    int t = blockIdx.x * 256 + threadIdx.x;
    int l = t >> 11;
    int rem = t & 2047;
    int ks = rem >> 9;
    int rem2 = rem & 511;
    int nt = rem2 >> 6;
    int L = rem2 & 63;
    const float* Wl = W + (size_t)l * FD * FD;
    int kbase = ks * 32 + ((L >> 4) << 3);
    int n = nt * 16 + (L & 15);
    v8s hv;
#pragma unroll
    for (int j = 0; j < 8; j++)
        hv[j] = (short)f2bf(Wl[(size_t)(kbase + j) * FD + n]);
    *(v8s*)(Whi + (size_t)t * 8) = hv;
}

// ---------- fused 64-layer network, one persistent kernel ----------
// v5: L2-cached gathers (sc0 loads) + write-through h stores (sc0 sc1,
// L2 never dirty) + ONE elected buffer_inv sc1 per XCD per layer for
// cross-XCD staleness. 8 invs/layer vs R2's 2048 wbl2+inv pairs.
__global__ __launch_bounds__(256, 8) void k_net(
        unsigned short* __restrict__ h0,
        unsigned short* __restrict__ h1,
        const int* __restrict__ offs,
        const int* __restrict__ col,
        const unsigned short* __restrict__ Whi,
        const float* __restrict__ dinv,
        const float* __restrict__ biases,
        const float* __restrict__ x,
        const float* __restrict__ cw,
        const float* __restrict__ cb,
        float* __restrict__ out,
        int* __restrict__ bar) {
    __shared__ unsigned short sA[MROW * SROW];
    __shared__ float sDinv[MROW];
    int tid = threadIdx.x;
    int lane = tid & 63;
    int w = tid >> 6;
    int row0 = blockIdx.x * MROW;
    int fg = lane >> 4;        // node subgroup 0..3
    int fl = lane & 15;        // feature chunk (8 feats = 16B)
    int grp = blockIdx.x & (BARGRP - 1);
    bool leader = (blockIdx.x < BARGRP);
    int xcc;                   // physical XCD id (0..7) — m09-verified getreg
    asm("s_getreg_b32 %0, hwreg(HW_REG_XCC_ID)" : "=s"(xcc));

    if (tid < MROW) sDinv[tid] = dinv[row0 + tid];

    // ---- layer-invariant prologue ----
    int nbase = row0 + w * 4;
    int4 ov = *(const int4*)(offs + nbase);
    int o4 = offs[nbase + 4];
    int B0 = ov.x;
    int Etot = o4 - B0;
    int node = nbase + fg;
    float dself = dinv[node];
    bool fast = (Etot <= 64);
    int cwin = 0, sg = 0, eg = 0, m = 0;
    if (fast) {
        cwin = (lane < Etot) ? col[B0 + lane] : 0;   // col window held 64 layers
        sg = ((fg == 0) ? ov.x : (fg == 1) ? ov.y : (fg == 2) ? ov.z : ov.w) - B0;
        eg = ((fg == 0) ? ov.y : (fg == 1) ? ov.z : (fg == 2) ? ov.w : o4) - B0;
        int len = eg - sg;
        m = max(len, __shfl_xor(len, 16));
        m = max(m, __shfl_xor(m, 32));      // wave-uniform max deg (4 groups)
    }

    for (int l = 0; l < NL; ++l) {
        const unsigned short* gin  = (l & 1) ? h0 : h1;  // l=0 reads h1 (g0)
        unsigned short* gout       = (l & 1) ? h1 : h0;
        const unsigned short* gf = gin + fl * 8;
        const unsigned short* Wl = Whi + (size_t)l * FD * FD;

        // ---- phase 1: gather + aggregate (L2-cached sc0 loads) ----
        if (fast) {
            float acc[8];
#pragma unroll
            for (int k = 0; k < 8; k++) acc[k] = 0.f;
            // self loop: for l>0 our own row is still in sA from the epilogue
            v8s selfv;
            if (l == 0) selfv = *(const v8s*)(gf + (size_t)node * FD);  // launch-boundary coherent
            else        selfv = *(const v8s*)&sA[(w * 4 + fg) * SROW + fl * 8];
            acc8_bf16(acc, selfv);
            for (int j = 0; j < m; j += 6) {
                int i0 = sg + j,     i1 = sg + j + 1, i2 = sg + j + 2;
                int i3 = sg + j + 3, i4 = sg + j + 4, i5 = sg + j + 5;
                bool p0 = i0 < eg, p1 = i1 < eg, p2 = i2 < eg;
                bool p3 = i3 < eg, p4 = i4 < eg, p5 = i5 < eg;
                int s0 = __shfl(cwin, i0 & 63);
                int s1 = __shfl(cwin, i1 & 63);
                int s2 = __shfl(cwin, i2 & 63);
                int s3 = __shfl(cwin, i3 & 63);
                int s4 = __shfl(cwin, i4 & 63);
                int s5 = __shfl(cwin, i5 & 63);
                const unsigned short* a0 = p0 ? (gf + (size_t)s0 * FD) : gf;
                const unsigned short* a1 = p1 ? (gf + (size_t)s1 * FD) : gf;
                const unsigned short* a2 = p2 ? (gf + (size_t)s2 * FD) : gf;
                const unsigned short* a3 = p3 ? (gf + (size_t)s3 * FD) : gf;
                const unsigned short* a4 = p4 ? (gf + (size_t)s4 * FD) : gf;
                const unsigned short* a5 = p5 ? (gf + (size_t)s5 * FD) : gf;
                v8s r0 = load16_l2(a0);
                v8s r1 = load16_l2(a1);
                v8s r2 = load16_l2(a2);
                v8s r3 = load16_l2(a3);
                v8s r4 = load16_l2(a4);
                v8s r5 = load16_l2(a5);
                wait_vm0();
                if (p0) acc8_bf16(acc, r0);
                if (p1) acc8_bf16(acc, r1);
                if (p2) acc8_bf16(acc, r2);
                if (p3) acc8_bf16(acc, r3);
                if (p4) acc8_bf16(acc, r4);
                if (p5) acc8_bf16(acc, r5);
            }
            unsigned pk[4];
#pragma unroll
            for (int k = 0; k < 4; k++) {
                pk[k] = (unsigned)f2bf(dself * acc[2 * k]) |
                        ((unsigned)f2bf(dself * acc[2 * k + 1]) << 16);
            }
            *(v8s*)&sA[(w * 4 + fg) * SROW + fl * 8] = *(v8s*)pk;
        } else {
            // rare path: per-node col loads, any degree
            for (int r = 0; r < 4; r++) {
                int nloc = w * 4 + r;
                int nd = row0 + nloc;
                float acc[8];
#pragma unroll
                for (int k = 0; k < 8; k++) acc[k] = 0.f;
                int b = offs[nd], e = offs[nd + 1];
                int deg = e - b;
                for (int base = 0; base < deg; base += 64) {
                    int n = min(deg - base, 64);
                    int c = (lane < n) ? col[b + base + lane] : 0;
                    for (int j = 0; j < n; j += 8) {
                        int e0 = j + fg, e1 = j + 4 + fg;
                        int s0 = __shfl(c, e0 & 63);
                        int s1 = __shfl(c, e1 & 63);
                        bool p0 = e0 < n, p1 = e1 < n;
                        const unsigned short* a0 = p0 ? (gf + (size_t)s0 * FD) : gf;
                        const unsigned short* a1 = p1 ? (gf + (size_t)s1 * FD) : gf;
                        v8s r0 = load16_l2(a0);
                        v8s r1 = load16_l2(a1);
                        wait_vm0();
                        if (p0) acc8_bf16(acc, r0);
                        if (p1) acc8_bf16(acc, r1);
                    }
                }
#pragma unroll
                for (int k = 0; k < 8; k++) {
                    acc[k] += __shfl_xor(acc[k], 16);
                    acc[k] += __shfl_xor(acc[k], 32);
                }
                v8s sv;
                if (l == 0) sv = *(const v8s*)(gf + (size_t)nd * FD);
                else        sv = *(const v8s*)&sA[nloc * SROW + fl * 8];
                acc8_bf16(acc, sv);
                if (fg == 0) {
                    float di = dinv[nd];
                    unsigned pk[4];
#pragma unroll
                    for (int k = 0; k < 4; k++) {
                        pk[k] = (unsigned)f2bf(di * acc[2 * k]) |
                                ((unsigned)f2bf(di * acc[2 * k + 1]) << 16);
                    }
                    *(v8s*)&sA[nloc * SROW + fl * 8] = *(v8s*)pk;
                }
            }
        }
        __syncthreads();

        // ---- phase 2: 16x128 @ 128x128 MFMA (A from LDS, W bf16 from L2) ----
        v4f a0 = (v4f){0.f, 0.f, 0.f, 0.f};
        v4f a1 = (v4f){0.f, 0.f, 0.f, 0.f};
#pragma unroll
        for (int ks = 0; ks < 4; ks++) {
            v8s ah = *(const v8s*)&sA[(lane & 15) * SROW + ks * 32 + ((lane >> 4) << 3)];
            size_t bo0 = ((size_t)(ks * 8 + w * 2) * 64 + lane) * 8;
            size_t bo1 = ((size_t)(ks * 8 + w * 2 + 1) * 64 + lane) * 8;
            v8s bh0 = *(const v8s*)(Wl + bo0);
            v8s bh1 = *(const v8s*)(Wl + bo1);
            a0 = __builtin_amdgcn_mfma_f32_16x16x32_bf16(ah, bh0, a0, 0, 0, 0);
            a1 = __builtin_amdgcn_mfma_f32_16x16x32_bf16(ah, bh1, a1, 0, 0, 0);
        }
        __syncthreads();  // before reusing sA

        // ---- epilogue: bias + relu (+ dinv unless last), into sA ----
        bool last = (l == NL - 1);
        float bb0 = biases[(size_t)l * FD + w * 32 + (lane & 15)];
        float bb1 = biases[(size_t)l * FD + w * 32 + 16 + (lane & 15)];
#pragma unroll
        for (int nt = 0; nt < 2; nt++) {
            int col_l = w * 32 + nt * 16 + (lane & 15);
            float bb = nt ? bb1 : bb0;
            v4f a = nt ? a1 : a0;
#pragma unroll
            for (int rg = 0; rg < 4; rg++) {
                int row_l = ((lane >> 4) << 2) + rg;
                float v = fmaxf(a[rg] + bb, 0.f);
                if (!last) v *= sDinv[row_l];
                sA[row_l * SROW + col_l] = f2bf(v);
            }
        }
        __syncthreads();

        if (!last) {
            // store h for other blocks' gathers — write-through coherent
            int orow = tid >> 4;
            int ocol = (tid & 15) * 8;
            v8s hv = *(const v8s*)&sA[orow * SROW + ocol];
            store16_sc(gout + (size_t)(row0 + orow) * FD + ocol, hv);
            wait_vm0();        // store ack'd at coherent point before arrive

            // ---- device-wide barrier + elected per-XCD L2 invalidate ----
            __syncthreads();
            if (tid == 0) {
                int a = atomicAdd(&bar[grp * 64], 1);            // group arrive
                if (a == GRPSZ * (l + 1) - 1) {
                    int r = atomicAdd(&bar[64 * 64], 1);         // root arrive
                    if (r == BARGRP * (l + 1) - 1) {
                        __hip_atomic_store(&bar[65 * 64], l + 1,
                                           __ATOMIC_RELAXED, __HIP_MEMORY_SCOPE_AGENT);
                    }
                }
                if (leader) {
                    while (__hip_atomic_load(&bar[65 * 64], __ATOMIC_RELAXED,
                                             __HIP_MEMORY_SCOPE_AGENT) < l + 1)
                        __builtin_amdgcn_s_sleep(4);
                    __hip_atomic_store(&bar[(66 + grp) * 64], l + 1,
                                       __ATOMIC_RELAXED, __HIP_MEMORY_SCOPE_AGENT);
                } else {
                    while (__hip_atomic_load(&bar[(66 + grp) * 64], __ATOMIC_RELAXED,
                                             __HIP_MEMORY_SCOPE_AGENT) < l + 1)
                        __builtin_amdgcn_s_sleep(16);
                }
                // all stores (every XCD) are at the coherent point now.
                // Elect ONE block per XCD to invalidate this XCD's L2 so
                // next layer's cached gathers can't see stale h lines.
                int old = __hip_atomic_fetch_max(&bar[(130 + xcc) * 64], l + 1,
                                                 __ATOMIC_RELAXED,
                                                 __HIP_MEMORY_SCOPE_AGENT);
                if (old <= l) {
                    asm volatile("buffer_inv sc1" ::: "memory");
                    asm volatile("s_waitcnt vmcnt(0)" ::: "memory");
                    __hip_atomic_store(&bar[(138 + xcc) * 64], l + 1,
                                       __ATOMIC_RELAXED, __HIP_MEMORY_SCOPE_AGENT);
                } else {
                    while (__hip_atomic_load(&bar[(138 + xcc) * 64], __ATOMIC_RELAXED,
                                             __HIP_MEMORY_SCOPE_AGENT) < l + 1)
                        __builtin_amdgcn_s_sleep(2);
                }
                asm volatile("" ::: "memory");
            }
            __syncthreads();
        } else {
            // ---- fused classifier: out = (h + x) @ cw + cb, h in sA ----
            int row = tid >> 4;          // 0..15
            int t = tid & 15;            // feature octet
            int nd = row0 + row;
            const unsigned short* hr = &sA[row * SROW + t * 8];
            const float* xr = x + (size_t)nd * FD + t * 8;
            float xv[8];
            *(float4*)&xv[0] = *(const float4*)xr;
            *(float4*)&xv[4] = *(const float4*)(xr + 4);
            float p0 = 0.f, p1 = 0.f, p2 = 0.f, p3 = 0.f;
#pragma unroll
            for (int j = 0; j < 8; j++) {
                float s = bf2f(hr[j]) + xv[j];
                float4 wv = *(const float4*)(cw + (size_t)(t * 8 + j) * 4);
                p0 += s * wv.x; p1 += s * wv.y; p2 += s * wv.z; p3 += s * wv.w;
            }
#pragma unroll
            for (int off = 1; off < 16; off <<= 1) {
                p0 += __shfl_xor(p0, off);
                p1 += __shfl_xor(p1, off);
                p2 += __shfl_xor(p2, off);
                p3 += __shfl_xor(p3, off);
            }
            if (t == 0) {
                float4 r = make_float4(p0 + cb[0], p1 + cb[1], p2 + cb[2], p3 + cb[3]);
                *(float4*)(out + (size_t)nd * 4) = r;
            }
        }
    }
}

extern "C" void kernel_launch(void* const* d_in, const int* in_sizes, int n_in,
                              void* d_out, int out_size, void* d_ws, size_t ws_size,
                              hipStream_t stream) {
    const float* x       = (const float*)d_in[0];
    const int* ei        = (const int*)d_in[1];       // [2][EE], int32
    const float* weights = (const float*)d_in[2];
    const float* biases  = (const float*)d_in[3];
    const float* cls_w   = (const float*)d_in[4];
    const float* cls_b   = (const float*)d_in[5];
    float* out = (float*)d_out;

    char* ws = (char*)d_ws;
    size_t off = 0;
    auto alloc = [&](size_t bytes) -> void* {
        off = (off + 255) & ~(size_t)255;
        void* p = ws + off;
        off += bytes;
        return p;
    };
    int*   cnt    = (int*)alloc((size_t)NN * 4);
    int*   cursor = (int*)alloc((size_t)NN * 4);
    float* dinv   = (float*)alloc((size_t)NN * 4);
    int*   offs   = (int*)alloc((size_t)(NN + 1) * 4);
    int*   bsum   = (int*)alloc((size_t)128 * 4);
    int*   boff   = (int*)alloc((size_t)128 * 4);
    int*   bar    = (int*)alloc((size_t)BAR_INTS * 4);
    int*   col    = (int*)alloc((size_t)EE * 4);
    unsigned short* Whi = (unsigned short*)alloc((size_t)NL * FD * FD * 2);
    unsigned short* h0  = (unsigned short*)alloc((size_t)NN * FD * 2);
    unsigned short* h1  = (unsigned short*)alloc((size_t)NN * FD * 2);

    const int* srcv = ei;
    const int* dstv = ei + EE;

    hipMemsetAsync(cnt, 0, (size_t)NN * 4, stream);
    hipMemsetAsync(cursor, 0, (size_t)NN * 4, stream);
    hipMemsetAsync(bar, 0, (size_t)BAR_INTS * 4, stream);
    k_deg<<<EE / 256, 256, 0, stream>>>(dstv, cnt);
    k_dinv<<<NN / 256, 256, 0, stream>>>(cnt, dinv);
    k_scanA<<<128, 256, 0, stream>>>(cnt, bsum);
    k_scanB<<<1, 128, 0, stream>>>(bsum, boff, offs);
    k_scanC<<<128, 256, 0, stream>>>(cnt, boff, offs);
    k_fill<<<EE / 256, 256, 0, stream>>>(srcv, dstv, offs, cursor, col);
    k_wcast<<<NL * 2048 / 256, 256, 0, stream>>>(weights, Whi);
    k_xcast<<<NN * FD / 2048, 256, 0, stream>>>(x, dinv, h1);  // g0 in h1

    // all 64 layers + classifier in ONE persistent kernel
    k_net<<<NBLK, 256, 0, stream>>>(h0, h1, offs, col, Whi, dinv, biases,
                                    x, cls_w, cls_b, out, bar);
}

// Round 6
// 1028.870 us; speedup vs baseline: 1.5609x; 1.4524x over previous
//
#include <hip/hip_runtime.h>
#include <hip/hip_bf16.h>

#define NN 32768
#define EE 262144
#define FD 128
#define NL 64
#define MROW 32     // nodes per block — 1024 blocks x 512 thr, 4/CU, 32 waves/CU
#define SROW 132    // LDS row stride (ushorts)
#define NBLKL (NN / MROW)   // 1024 blocks per layer

typedef short v8s __attribute__((ext_vector_type(8)));
typedef float v4f __attribute__((ext_vector_type(4)));

__device__ __forceinline__ unsigned short f2bf(float x) {
    unsigned u = __builtin_bit_cast(unsigned, x);
    u += 0x7fffu + ((u >> 16) & 1u);
    return (unsigned short)(u >> 16);
}
__device__ __forceinline__ float bf2f(unsigned short h) {
    unsigned u = ((unsigned)h) << 16;
    return __builtin_bit_cast(float, u);
}
// accumulate 8 bf16 (packed in v8s) into acc[8]
__device__ __forceinline__ void acc8_bf16(float* acc, v8s r) {
    const int* d = (const int*)&r;
#pragma unroll
    for (int k = 0; k < 4; k++) {
        unsigned u = (unsigned)d[k];
        acc[2 * k]     += __builtin_bit_cast(float, u << 16);
        acc[2 * k + 1] += __builtin_bit_cast(float, u & 0xffff0000u);
    }
}

// ---------- setup ----------
__global__ __launch_bounds__(256) void k_deg(const int* __restrict__ dst,
                                             int* __restrict__ cnt) {
    int e = blockIdx.x * 256 + threadIdx.x;
    if (e < EE) atomicAdd(&cnt[dst[e]], 1);
}

// hierarchical scan
__global__ __launch_bounds__(256) void k_scanA(const int* __restrict__ cnt,
                                               int* __restrict__ bsum) {
    __shared__ int ws[4];
    int tid = threadIdx.x;
    int v = cnt[blockIdx.x * 256 + tid];
    int x = v;
#pragma unroll
    for (int off = 1; off < 64; off <<= 1) x += __shfl_xor(x, off);
    if ((tid & 63) == 0) ws[tid >> 6] = x;
    __syncthreads();
    if (tid == 0) bsum[blockIdx.x] = ws[0] + ws[1] + ws[2] + ws[3];
}
__global__ __launch_bounds__(128) void k_scanB(const int* __restrict__ bsum,
                                               int* __restrict__ boff,
                                               int* __restrict__ offs) {
    __shared__ int s0;
    int tid = threadIdx.x;
    int v = bsum[tid];
    int lane = tid & 63, w = tid >> 6;
    int x = v;
#pragma unroll
    for (int off = 1; off < 64; off <<= 1) {
        int y = __shfl_up(x, off);
        if (lane >= off) x += y;
    }
    if (tid == 63) s0 = x;
    __syncthreads();
    int excl = x - v + (w ? s0 : 0);
    boff[tid] = excl;
    if (tid == 127) offs[NN] = excl + v;
}
// scanC + dinv fused (one fewer launch)
__global__ __launch_bounds__(256) void k_scanC(const int* __restrict__ cnt,
                                               const int* __restrict__ boff,
                                               int* __restrict__ offs,
                                               float* __restrict__ dinv) {
    __shared__ int ws[4];
    int tid = threadIdx.x;
    int i = blockIdx.x * 256 + tid;
    int v = cnt[i];
    int lane = tid & 63, w = tid >> 6;
    int x = v;
#pragma unroll
    for (int off = 1; off < 64; off <<= 1) {
        int y = __shfl_up(x, off);
        if (lane >= off) x += y;
    }
    if (lane == 63) ws[w] = x;
    __syncthreads();
    int wexcl = 0;
#pragma unroll
    for (int k = 0; k < 4; k++) if (k < w) wexcl += ws[k];
    offs[i] = boff[blockIdx.x] + wexcl + x - v;
    dinv[i] = rsqrtf((float)v + 1.0f);
}

__global__ __launch_bounds__(256) void k_fill(const int* __restrict__ src,
                                              const int* __restrict__ dst,
                                              const int* __restrict__ offs,
                                              int* __restrict__ cursor,
                                              int* __restrict__ col) {
    int e = blockIdx.x * 256 + threadIdx.x;
    if (e >= EE) return;
    int s = src[e], d = dst[e];
    int slot = atomicAdd(&cursor[d], 1);
    col[offs[d] + slot] = s;
}

// merged: weight cast (blocks 0..511) + g0 = bf16(dinv*x) (blocks 512..2559)
__global__ __launch_bounds__(256) void k_wxcast(const float* __restrict__ W,
                                                unsigned short* __restrict__ Whi,
                                                const float* __restrict__ x,
                                                const float* __restrict__ dinv,
                                                unsigned short* __restrict__ g) {
    int b = blockIdx.x;
    if (b < NL * 2048 / 256) {
        // fp32 W -> bf16 in MFMA B-fragment order:
        // [l][kstep(4)][ntile(8)][lane(64)][j(8)]; k=ks*32+(lane>>4)*8+j, n=nt*16+(lane&15)
        int t = b * 256 + threadIdx.x;
        int l = t >> 11;
        int rem = t & 2047;
        int ks = rem >> 9;
        int rem2 = rem & 511;
        int nt = rem2 >> 6;
        int L = rem2 & 63;
        const float* Wl = W + (size_t)l * FD * FD;
        int kbase = ks * 32 + ((L >> 4) << 3);
        int n = nt * 16 + (L & 15);
        v8s hv;
#pragma unroll
        for (int j = 0; j < 8; j++)
            hv[j] = (short)f2bf(Wl[(size_t)(kbase + j) * FD + n]);
        *(v8s*)(Whi + (size_t)t * 8) = hv;
    } else {
        int i = (b - NL * 2048 / 256) * 256 + threadIdx.x;
        float di = dinv[(i * 8) >> 7];
        float4 a = *(const float4*)(x + (size_t)i * 8);
        float4 c = *(const float4*)(x + (size_t)i * 8 + 4);
        v8s o;
        o[0] = (short)f2bf(di * a.x); o[1] = (short)f2bf(di * a.y);
        o[2] = (short)f2bf(di * a.z); o[3] = (short)f2bf(di * a.w);
        o[4] = (short)f2bf(di * c.x); o[5] = (short)f2bf(di * c.y);
        o[6] = (short)f2bf(di * c.z); o[7] = (short)f2bf(di * c.w);
        *(v8s*)(g + (size_t)i * 8) = o;
    }
}

// ---------- fused layer: g_out = dinv * relu( (dinv*(sum g)) @ W + b ) ----
// Per-launch (coherence + caching free at launch boundary — the persistent
// arc R1-R5 proved every in-kernel coherence scheme pays ~the full fabric
// price per layer and floors at ~1.4ms).
// MROW=32 / 512 thr / 1024 blocks: halved dispatch units vs round-0.
// 8 waves: wave w owns nodes w*4..w*4+3 for gather; phase-2 tile
// (row-tile w>>2, col-pair w&3). Last layer: classifier fused, no h store.
__global__ __launch_bounds__(512, 8) void k_layer(
        const unsigned short* __restrict__ g,
        const int* __restrict__ offs,
        const int* __restrict__ col,
        const unsigned short* __restrict__ Whi,
        const float* __restrict__ dinv,
        const float* __restrict__ bias,
        unsigned short* __restrict__ gout,
        const float* __restrict__ x,
        const float* __restrict__ cw,
        const float* __restrict__ cb,
        float* __restrict__ out,
        int last) {
    __shared__ unsigned short sA[MROW * SROW];
    __shared__ float sDinv[MROW];
    int tid = threadIdx.x;
    int lane = tid & 63;
    int w = tid >> 6;          // 0..7
    int row0 = blockIdx.x * MROW;
    int fg = lane >> 4;        // node subgroup 0..3 (one node per group)
    int fl = lane & 15;        // feature chunk (8 feats = 16B)
    const unsigned short* gf = g + fl * 8;

    if (tid < MROW) sDinv[tid] = dinv[row0 + tid];

    int nbase = row0 + w * 4;                      // multiple of 4 -> aligned
    int4 ov = *(const int4*)(offs + nbase);
    int o4 = offs[nbase + 4];
    int B0 = ov.x;
    int Etot = o4 - B0;

    if (Etot <= 64) {
        // fast path: one coalesced col window covers all 4 nodes
        int c = (lane < Etot) ? col[B0 + lane] : 0;
        int node = nbase + fg;
        int sg = ((fg == 0) ? ov.x : (fg == 1) ? ov.y : (fg == 2) ? ov.z : ov.w) - B0;
        int eg = ((fg == 0) ? ov.y : (fg == 1) ? ov.z : (fg == 2) ? ov.w : o4) - B0;
        int len = eg - sg;
        int m = max(len, __shfl_xor(len, 16));
        m = max(m, __shfl_xor(m, 32));      // max deg over the 4 groups
        float acc[8];
#pragma unroll
        for (int k = 0; k < 8; k++) acc[k] = 0.f;
        for (int j = 0; j < m; j += 6) {
            int i0 = sg + j,     i1 = sg + j + 1, i2 = sg + j + 2;
            int i3 = sg + j + 3, i4 = sg + j + 4, i5 = sg + j + 5;
            bool p0 = i0 < eg, p1 = i1 < eg, p2 = i2 < eg;
            bool p3 = i3 < eg, p4 = i4 < eg, p5 = i5 < eg;
            int s0 = __shfl(c, i0 & 63);
            int s1 = __shfl(c, i1 & 63);
            int s2 = __shfl(c, i2 & 63);
            int s3 = __shfl(c, i3 & 63);
            int s4 = __shfl(c, i4 & 63);
            int s5 = __shfl(c, i5 & 63);
            v8s r0, r1, r2, r3, r4, r5;
            if (p0) r0 = *(const v8s*)(gf + (size_t)s0 * FD);
            if (p1) r1 = *(const v8s*)(gf + (size_t)s1 * FD);
            if (p2) r2 = *(const v8s*)(gf + (size_t)s2 * FD);
            if (p3) r3 = *(const v8s*)(gf + (size_t)s3 * FD);
            if (p4) r4 = *(const v8s*)(gf + (size_t)s4 * FD);
            if (p5) r5 = *(const v8s*)(gf + (size_t)s5 * FD);
            if (p0) acc8_bf16(acc, r0);
            if (p1) acc8_bf16(acc, r1);
            if (p2) acc8_bf16(acc, r2);
            if (p3) acc8_bf16(acc, r3);
            if (p4) acc8_bf16(acc, r4);
            if (p5) acc8_bf16(acc, r5);
        }
        v8s selfv = *(const v8s*)(gf + (size_t)node * FD);
        acc8_bf16(acc, selfv);   // self loop
        float di = dinv[node];
        unsigned pk[4];
#pragma unroll
        for (int k = 0; k < 4; k++) {
            pk[k] = (unsigned)f2bf(di * acc[2 * k]) |
                    ((unsigned)f2bf(di * acc[2 * k + 1]) << 16);
        }
        *(v8s*)&sA[(w * 4 + fg) * SROW + fl * 8] = *(v8s*)pk;  // all lanes write
    } else {
        // rare path: per-node col loads, any degree
        for (int r = 0; r < 4; r++) {
            int nloc = w * 4 + r;
            int node = row0 + nloc;
            float acc[8];
#pragma unroll
            for (int k = 0; k < 8; k++) acc[k] = 0.f;
            int b = offs[node], e = offs[node + 1];
            int deg = e - b;
            for (int base = 0; base < deg; base += 64) {
                int n = min(deg - base, 64);
                int c = (lane < n) ? col[b + base + lane] : 0;
                for (int j = 0; j < n; j += 8) {
                    int e0 = j + fg, e1 = j + 4 + fg;
                    int s0 = __shfl(c, e0 & 63);
                    int s1 = __shfl(c, e1 & 63);
                    bool p0 = e0 < n, p1 = e1 < n;
                    v8s r0, r1;
                    if (p0) r0 = *(const v8s*)(gf + (size_t)s0 * FD);
                    if (p1) r1 = *(const v8s*)(gf + (size_t)s1 * FD);
                    if (p0) acc8_bf16(acc, r0);
                    if (p1) acc8_bf16(acc, r1);
                }
            }
#pragma unroll
            for (int k = 0; k < 8; k++) {
                acc[k] += __shfl_xor(acc[k], 16);
                acc[k] += __shfl_xor(acc[k], 32);
            }
            v8s sv = *(const v8s*)(gf + (size_t)node * FD);
            acc8_bf16(acc, sv);
            if (fg == 0) {
                float di = dinv[node];
                unsigned pk[4];
#pragma unroll
                for (int k = 0; k < 4; k++) {
                    pk[k] = (unsigned)f2bf(di * acc[2 * k]) |
                            ((unsigned)f2bf(di * acc[2 * k + 1]) << 16);
                }
                *(v8s*)&sA[nloc * SROW + fl * 8] = *(v8s*)pk;
            }
        }
    }
    __syncthreads();

    // phase 2: 32x128 @ 128x128 MFMA (A from LDS, W bf16 from L2)
    // wave w: row-tile rt = w>>2 (16 rows), col tiles wc*2, wc*2+1
    int rt = w >> 2;
    int wc = w & 3;
    v4f a0 = (v4f){0.f, 0.f, 0.f, 0.f};
    v4f a1 = (v4f){0.f, 0.f, 0.f, 0.f};
#pragma unroll
    for (int ks = 0; ks < 4; ks++) {
        v8s ah = *(const v8s*)&sA[(rt * 16 + (lane & 15)) * SROW + ks * 32 + ((lane >> 4) << 3)];
        size_t bo0 = ((size_t)(ks * 8 + wc * 2) * 64 + lane) * 8;
        size_t bo1 = ((size_t)(ks * 8 + wc * 2 + 1) * 64 + lane) * 8;
        v8s bh0 = *(const v8s*)(Whi + bo0);
        v8s bh1 = *(const v8s*)(Whi + bo1);
        a0 = __builtin_amdgcn_mfma_f32_16x16x32_bf16(ah, bh0, a0, 0, 0, 0);
        a1 = __builtin_amdgcn_mfma_f32_16x16x32_bf16(ah, bh1, a1, 0, 0, 0);
    }
    __syncthreads();  // before reusing sA

    // epilogue: bias + relu (+ dinv unless last), into sA
    float bb0 = bias[wc * 32 + (lane & 15)];
    float bb1 = bias[wc * 32 + 16 + (lane & 15)];
#pragma unroll
    for (int nt = 0; nt < 2; nt++) {
        int col_l = wc * 32 + nt * 16 + (lane & 15);
        float bb = nt ? bb1 : bb0;
        v4f a = nt ? a1 : a0;
#pragma unroll
        for (int rg = 0; rg < 4; rg++) {
            int row_l = rt * 16 + ((lane >> 4) << 2) + rg;
            float v = fmaxf(a[rg] + bb, 0.f);
            if (!last) v *= sDinv[row_l];
            sA[row_l * SROW + col_l] = f2bf(v);
        }
    }
    __syncthreads();

    if (!last) {
        // coalesced store of 32 rows (512 thr x 16B)
        int orow = tid >> 4;
        int ocol = (tid & 15) * 8;
        *(v8s*)(gout + (size_t)(row0 + orow) * FD + ocol) =
            *(const v8s*)&sA[orow * SROW + ocol];
    } else {
        // fused classifier: out = (h + x) @ cw + cb, h (raw relu) in sA
        int row = tid >> 4;          // 0..31
        int t = tid & 15;            // feature octet
        int nd = row0 + row;
        const unsigned short* hr = &sA[row * SROW + t * 8];
        const float* xr = x + (size_t)nd * FD + t * 8;
        float xv[8];
        *(float4*)&xv[0] = *(const float4*)xr;
        *(float4*)&xv[4] = *(const float4*)(xr + 4);
        float p0 = 0.f, p1 = 0.f, p2 = 0.f, p3 = 0.f;
#pragma unroll
        for (int j = 0; j < 8; j++) {
            float s = bf2f(hr[j]) + xv[j];
            float4 wv = *(const float4*)(cw + (size_t)(t * 8 + j) * 4);
            p0 += s * wv.x; p1 += s * wv.y; p2 += s * wv.z; p3 += s * wv.w;
        }
#pragma unroll
        for (int off = 1; off < 16; off <<= 1) {
            p0 += __shfl_xor(p0, off);
            p1 += __shfl_xor(p1, off);
            p2 += __shfl_xor(p2, off);
            p3 += __shfl_xor(p3, off);
        }
        if (t == 0) {
            float4 r = make_float4(p0 + cb[0], p1 + cb[1], p2 + cb[2], p3 + cb[3]);
            *(float4*)(out + (size_t)nd * 4) = r;
        }
    }
}

extern "C" void kernel_launch(void* const* d_in, const int* in_sizes, int n_in,
                              void* d_out, int out_size, void* d_ws, size_t ws_size,
                              hipStream_t stream) {
    const float* x       = (const float*)d_in[0];
    const int* ei        = (const int*)d_in[1];       // [2][EE], int32
    const float* weights = (const float*)d_in[2];
    const float* biases  = (const float*)d_in[3];
    const float* cls_w   = (const float*)d_in[4];
    const float* cls_b   = (const float*)d_in[5];
    float* out = (float*)d_out;

    char* ws = (char*)d_ws;
    size_t off = 0;
    auto alloc = [&](size_t bytes) -> void* {
        off = (off + 255) & ~(size_t)255;
        void* p = ws + off;
        off += bytes;
        return p;
    };
    int*   cnt    = (int*)alloc((size_t)NN * 4);
    int*   cursor = (int*)alloc((size_t)NN * 4);
    float* dinv   = (float*)alloc((size_t)NN * 4);
    int*   offs   = (int*)alloc((size_t)(NN + 1) * 4);
    int*   bsum   = (int*)alloc((size_t)128 * 4);
    int*   boff   = (int*)alloc((size_t)128 * 4);
    int*   col    = (int*)alloc((size_t)EE * 4);
    unsigned short* Whi = (unsigned short*)alloc((size_t)NL * FD * FD * 2);
    unsigned short* h0  = (unsigned short*)alloc((size_t)NN * FD * 2);
    unsigned short* h1  = (unsigned short*)alloc((size_t)NN * FD * 2);

    const int* srcv = ei;
    const int* dstv = ei + EE;

    hipMemsetAsync(cnt, 0, (size_t)NN * 4, stream);
    hipMemsetAsync(cursor, 0, (size_t)NN * 4, stream);
    k_deg<<<EE / 256, 256, 0, stream>>>(dstv, cnt);
    k_scanA<<<128, 256, 0, stream>>>(cnt, bsum);
    k_scanB<<<1, 128, 0, stream>>>(bsum, boff, offs);
    k_scanC<<<128, 256, 0, stream>>>(cnt, boff, offs, dinv);
    k_fill<<<EE / 256, 256, 0, stream>>>(srcv, dstv, offs, cursor, col);
    k_wxcast<<<NL * 2048 / 256 + NN * FD / 2048, 256, 0, stream>>>(
        weights, Whi, x, dinv, h1);  // Whi + g0 (in h1)

    const unsigned short* gin = h1;
    for (int l = 0; l < NL; l++) {
        unsigned short* gout = (l & 1) ? h1 : h0;
        k_layer<<<NBLKL, 512, 0, stream>>>(gin, offs, col,
                                           Whi + (size_t)l * FD * FD,
                                           dinv, biases + (size_t)l * FD,
                                           gout, x, cls_w, cls_b, out,
                                           l == NL - 1);
        gin = gout;
    }
}

// Round 7
// 1013.307 us; speedup vs baseline: 1.5849x; 1.0154x over previous
//
#include <hip/hip_runtime.h>
#include <hip/hip_bf16.h>

#define NN 32768
#define EE 262144
#define FD 128
#define NL 64
#define MROW 16     // nodes per block — 2048 blocks, 8/CU, 32 waves/CU (R0-proven fastest)
#define SROW 132    // LDS row stride (ushorts)

typedef short v8s __attribute__((ext_vector_type(8)));
typedef float v4f __attribute__((ext_vector_type(4)));

__device__ __forceinline__ unsigned short f2bf(float x) {
    unsigned u = __builtin_bit_cast(unsigned, x);
    u += 0x7fffu + ((u >> 16) & 1u);
    return (unsigned short)(u >> 16);
}
__device__ __forceinline__ float bf2f(unsigned short h) {
    unsigned u = ((unsigned)h) << 16;
    return __builtin_bit_cast(float, u);
}
// accumulate 8 bf16 (packed in v8s) into acc[8]
__device__ __forceinline__ void acc8_bf16(float* acc, v8s r) {
    const int* d = (const int*)&r;
#pragma unroll
    for (int k = 0; k < 4; k++) {
        unsigned u = (unsigned)d[k];
        acc[2 * k]     += __builtin_bit_cast(float, u << 16);
        acc[2 * k + 1] += __builtin_bit_cast(float, u & 0xffff0000u);
    }
}

// ---------- setup ----------
__global__ __launch_bounds__(256) void k_deg(const int* __restrict__ dst,
                                             int* __restrict__ cnt) {
    int e = blockIdx.x * 256 + threadIdx.x;
    if (e < EE) atomicAdd(&cnt[dst[e]], 1);
}

// hierarchical scan
__global__ __launch_bounds__(256) void k_scanA(const int* __restrict__ cnt,
                                               int* __restrict__ bsum) {
    __shared__ int ws[4];
    int tid = threadIdx.x;
    int v = cnt[blockIdx.x * 256 + tid];
    int x = v;
#pragma unroll
    for (int off = 1; off < 64; off <<= 1) x += __shfl_xor(x, off);
    if ((tid & 63) == 0) ws[tid >> 6] = x;
    __syncthreads();
    if (tid == 0) bsum[blockIdx.x] = ws[0] + ws[1] + ws[2] + ws[3];
}
__global__ __launch_bounds__(128) void k_scanB(const int* __restrict__ bsum,
                                               int* __restrict__ boff,
                                               int* __restrict__ offs) {
    __shared__ int s0;
    int tid = threadIdx.x;
    int v = bsum[tid];
    int lane = tid & 63, w = tid >> 6;
    int x = v;
#pragma unroll
    for (int off = 1; off < 64; off <<= 1) {
        int y = __shfl_up(x, off);
        if (lane >= off) x += y;
    }
    if (tid == 63) s0 = x;
    __syncthreads();
    int excl = x - v + (w ? s0 : 0);
    boff[tid] = excl;
    if (tid == 127) offs[NN] = excl + v;
}
// scanC + dinv fused (R6-proven)
__global__ __launch_bounds__(256) void k_scanC(const int* __restrict__ cnt,
                                               const int* __restrict__ boff,
                                               int* __restrict__ offs,
                                               float* __restrict__ dinv) {
    __shared__ int ws[4];
    int tid = threadIdx.x;
    int i = blockIdx.x * 256 + tid;
    int v = cnt[i];
    int lane = tid & 63, w = tid >> 6;
    int x = v;
#pragma unroll
    for (int off = 1; off < 64; off <<= 1) {
        int y = __shfl_up(x, off);
        if (lane >= off) x += y;
    }
    if (lane == 63) ws[w] = x;
    __syncthreads();
    int wexcl = 0;
#pragma unroll
    for (int k = 0; k < 4; k++) if (k < w) wexcl += ws[k];
    offs[i] = boff[blockIdx.x] + wexcl + x - v;
    dinv[i] = rsqrtf((float)v + 1.0f);
}

// merged fill + wcast + xcast: one launch instead of three.
// blocks [0,1024): CSR fill; [1024,1536): W->bf16 fragment cast;
// [1536,3584): g0 = bf16(dinv*x).
__global__ __launch_bounds__(256) void k_prep(const int* __restrict__ src,
                                              const int* __restrict__ dst,
                                              const int* __restrict__ offs,
                                              int* __restrict__ cursor,
                                              int* __restrict__ col,
                                              const float* __restrict__ W,
                                              unsigned short* __restrict__ Whi,
                                              const float* __restrict__ x,
                                              const float* __restrict__ dinv,
                                              unsigned short* __restrict__ g) {
    int b = blockIdx.x;
    if (b < EE / 256) {
        int e = b * 256 + threadIdx.x;
        int s = src[e], d = dst[e];
        int slot = atomicAdd(&cursor[d], 1);
        col[offs[d] + slot] = s;
    } else if (b < EE / 256 + NL * 2048 / 256) {
        // fp32 W -> bf16 in MFMA B-fragment order:
        // [l][kstep(4)][ntile(8)][lane(64)][j(8)]; k=ks*32+(lane>>4)*8+j, n=nt*16+(lane&15)
        int t = (b - EE / 256) * 256 + threadIdx.x;
        int l = t >> 11;
        int rem = t & 2047;
        int ks = rem >> 9;
        int rem2 = rem & 511;
        int nt = rem2 >> 6;
        int L = rem2 & 63;
        const float* Wl = W + (size_t)l * FD * FD;
        int kbase = ks * 32 + ((L >> 4) << 3);
        int n = nt * 16 + (L & 15);
        v8s hv;
#pragma unroll
        for (int j = 0; j < 8; j++)
            hv[j] = (short)f2bf(Wl[(size_t)(kbase + j) * FD + n]);
        *(v8s*)(Whi + (size_t)t * 8) = hv;
    } else {
        int i = (b - EE / 256 - NL * 2048 / 256) * 256 + threadIdx.x;
        float di = dinv[(i * 8) >> 7];
        float4 a = *(const float4*)(x + (size_t)i * 8);
        float4 c = *(const float4*)(x + (size_t)i * 8 + 4);
        v8s o;
        o[0] = (short)f2bf(di * a.x); o[1] = (short)f2bf(di * a.y);
        o[2] = (short)f2bf(di * a.z); o[3] = (short)f2bf(di * a.w);
        o[4] = (short)f2bf(di * c.x); o[5] = (short)f2bf(di * c.y);
        o[6] = (short)f2bf(di * c.z); o[7] = (short)f2bf(di * c.w);
        *(v8s*)(g + (size_t)i * 8) = o;
    }
}

// ---------- fused layer: g_out = dinv * relu( (dinv*(sum g)) @ W + b ) ----
// R0 structure (MROW=16/256thr, fastest measured per-layer) + R6's proven
// last-layer classifier fusion (no h store, no k_cls launch, no h reload).
__global__ __launch_bounds__(256, 8) void k_layer(
        const unsigned short* __restrict__ g,
        const int* __restrict__ offs,
        const int* __restrict__ col,
        const unsigned short* __restrict__ Whi,
        const float* __restrict__ dinv,
        const float* __restrict__ bias,
        unsigned short* __restrict__ gout,
        const float* __restrict__ x,
        const float* __restrict__ cw,
        const float* __restrict__ cb,
        float* __restrict__ out,
        int last) {
    __shared__ unsigned short sA[MROW * SROW];
    __shared__ float sDinv[MROW];
    int tid = threadIdx.x;
    int lane = tid & 63;
    int w = tid >> 6;
    int row0 = blockIdx.x * MROW;
    int fg = lane >> 4;        // node subgroup 0..3 (one node per group)
    int fl = lane & 15;        // feature chunk (8 feats = 16B)
    const unsigned short* gf = g + fl * 8;

    if (tid < MROW) sDinv[tid] = dinv[row0 + tid];

    int nbase = row0 + w * 4;                      // multiple of 4 -> aligned
    int4 ov = *(const int4*)(offs + nbase);
    int o4 = offs[nbase + 4];
    int B0 = ov.x;
    int Etot = o4 - B0;

    if (Etot <= 64) {
        // fast path: one coalesced col window covers all 4 nodes
        int c = (lane < Etot) ? col[B0 + lane] : 0;
        int node = nbase + fg;
        int sg = ((fg == 0) ? ov.x : (fg == 1) ? ov.y : (fg == 2) ? ov.z : ov.w) - B0;
        int eg = ((fg == 0) ? ov.y : (fg == 1) ? ov.z : (fg == 2) ? ov.w : o4) - B0;
        int len = eg - sg;
        int m = max(len, __shfl_xor(len, 16));
        m = max(m, __shfl_xor(m, 32));      // max deg over the 4 groups
        float acc[8];
#pragma unroll
        for (int k = 0; k < 8; k++) acc[k] = 0.f;
        for (int j = 0; j < m; j += 6) {
            int i0 = sg + j,     i1 = sg + j + 1, i2 = sg + j + 2;
            int i3 = sg + j + 3, i4 = sg + j + 4, i5 = sg + j + 5;
            bool p0 = i0 < eg, p1 = i1 < eg, p2 = i2 < eg;
            bool p3 = i3 < eg, p4 = i4 < eg, p5 = i5 < eg;
            int s0 = __shfl(c, i0 & 63);
            int s1 = __shfl(c, i1 & 63);
            int s2 = __shfl(c, i2 & 63);
            int s3 = __shfl(c, i3 & 63);
            int s4 = __shfl(c, i4 & 63);
            int s5 = __shfl(c, i5 & 63);
            v8s r0, r1, r2, r3, r4, r5;
            if (p0) r0 = *(const v8s*)(gf + (size_t)s0 * FD);
            if (p1) r1 = *(const v8s*)(gf + (size_t)s1 * FD);
            if (p2) r2 = *(const v8s*)(gf + (size_t)s2 * FD);
            if (p3) r3 = *(const v8s*)(gf + (size_t)s3 * FD);
            if (p4) r4 = *(const v8s*)(gf + (size_t)s4 * FD);
            if (p5) r5 = *(const v8s*)(gf + (size_t)s5 * FD);
            if (p0) acc8_bf16(acc, r0);
            if (p1) acc8_bf16(acc, r1);
            if (p2) acc8_bf16(acc, r2);
            if (p3) acc8_bf16(acc, r3);
            if (p4) acc8_bf16(acc, r4);
            if (p5) acc8_bf16(acc, r5);
        }
        v8s selfv = *(const v8s*)(gf + (size_t)node * FD);
        acc8_bf16(acc, selfv);   // self loop
        float di = dinv[node];
        unsigned pk[4];
#pragma unroll
        for (int k = 0; k < 4; k++) {
            pk[k] = (unsigned)f2bf(di * acc[2 * k]) |
                    ((unsigned)f2bf(di * acc[2 * k + 1]) << 16);
        }
        *(v8s*)&sA[(w * 4 + fg) * SROW + fl * 8] = *(v8s*)pk;  // all lanes write
    } else {
        // rare path: per-node col loads, any degree
        for (int r = 0; r < 4; r++) {
            int nloc = w * 4 + r;
            int node = row0 + nloc;
            float acc[8];
#pragma unroll
            for (int k = 0; k < 8; k++) acc[k] = 0.f;
            int b = offs[node], e = offs[node + 1];
            int deg = e - b;
            for (int base = 0; base < deg; base += 64) {
                int n = min(deg - base, 64);
                int c = (lane < n) ? col[b + base + lane] : 0;
                for (int j = 0; j < n; j += 8) {
                    int e0 = j + fg, e1 = j + 4 + fg;
                    int s0 = __shfl(c, e0 & 63);
                    int s1 = __shfl(c, e1 & 63);
                    bool p0 = e0 < n, p1 = e1 < n;
                    v8s r0, r1;
                    if (p0) r0 = *(const v8s*)(gf + (size_t)s0 * FD);
                    if (p1) r1 = *(const v8s*)(gf + (size_t)s1 * FD);
                    if (p0) acc8_bf16(acc, r0);
                    if (p1) acc8_bf16(acc, r1);
                }
            }
#pragma unroll
            for (int k = 0; k < 8; k++) {
                acc[k] += __shfl_xor(acc[k], 16);
                acc[k] += __shfl_xor(acc[k], 32);
            }
            v8s sv = *(const v8s*)(gf + (size_t)node * FD);
            acc8_bf16(acc, sv);
            if (fg == 0) {
                float di = dinv[node];
                unsigned pk[4];
#pragma unroll
                for (int k = 0; k < 4; k++) {
                    pk[k] = (unsigned)f2bf(di * acc[2 * k]) |
                            ((unsigned)f2bf(di * acc[2 * k + 1]) << 16);
                }
                *(v8s*)&sA[nloc * SROW + fl * 8] = *(v8s*)pk;
            }
        }
    }
    __syncthreads();

    // phase 2: 16x128 @ 128x128 MFMA (A from LDS, W bf16 from L2)
    v4f a0 = (v4f){0.f, 0.f, 0.f, 0.f};
    v4f a1 = (v4f){0.f, 0.f, 0.f, 0.f};
#pragma unroll
    for (int ks = 0; ks < 4; ks++) {
        v8s ah = *(const v8s*)&sA[(lane & 15) * SROW + ks * 32 + ((lane >> 4) << 3)];
        size_t bo0 = ((size_t)(ks * 8 + w * 2) * 64 + lane) * 8;
        size_t bo1 = ((size_t)(ks * 8 + w * 2 + 1) * 64 + lane) * 8;
        v8s bh0 = *(const v8s*)(Whi + bo0);
        v8s bh1 = *(const v8s*)(Whi + bo1);
        a0 = __builtin_amdgcn_mfma_f32_16x16x32_bf16(ah, bh0, a0, 0, 0, 0);
        a1 = __builtin_amdgcn_mfma_f32_16x16x32_bf16(ah, bh1, a1, 0, 0, 0);
    }
    __syncthreads();  // before reusing sA

    // epilogue: bias + relu (+ dinv unless last), into sA
    float bb0 = bias[w * 32 + (lane & 15)];
    float bb1 = bias[w * 32 + 16 + (lane & 15)];
#pragma unroll
    for (int nt = 0; nt < 2; nt++) {
        int col_l = w * 32 + nt * 16 + (lane & 15);
        float bb = nt ? bb1 : bb0;
        v4f a = nt ? a1 : a0;
#pragma unroll
        for (int rg = 0; rg < 4; rg++) {
            int row_l = ((lane >> 4) << 2) + rg;
            float v = fmaxf(a[rg] + bb, 0.f);
            if (!last) v *= sDinv[row_l];
            sA[row_l * SROW + col_l] = f2bf(v);
        }
    }
    __syncthreads();

    if (!last) {
        // coalesced store of 16 rows (256 thr x 16B)
        int orow = tid >> 4;
        int ocol = (tid & 15) * 8;
        *(v8s*)(gout + (size_t)(row0 + orow) * FD + ocol) =
            *(const v8s*)&sA[orow * SROW + ocol];
    } else {
        // fused classifier: out = (h + x) @ cw + cb, h (raw relu) in sA
        int row = tid >> 4;          // 0..15
        int t = tid & 15;            // feature octet
        int nd = row0 + row;
        const unsigned short* hr = &sA[row * SROW + t * 8];
        const float* xr = x + (size_t)nd * FD + t * 8;
        float xv[8];
        *(float4*)&xv[0] = *(const float4*)xr;
        *(float4*)&xv[4] = *(const float4*)(xr + 4);
        float p0 = 0.f, p1 = 0.f, p2 = 0.f, p3 = 0.f;
#pragma unroll
        for (int j = 0; j < 8; j++) {
            float s = bf2f(hr[j]) + xv[j];
            float4 wv = *(const float4*)(cw + (size_t)(t * 8 + j) * 4);
            p0 += s * wv.x; p1 += s * wv.y; p2 += s * wv.z; p3 += s * wv.w;
        }
#pragma unroll
        for (int off = 1; off < 16; off <<= 1) {
            p0 += __shfl_xor(p0, off);
            p1 += __shfl_xor(p1, off);
            p2 += __shfl_xor(p2, off);
            p3 += __shfl_xor(p3, off);
        }
        if (t == 0) {
            float4 r = make_float4(p0 + cb[0], p1 + cb[1], p2 + cb[2], p3 + cb[3]);
            *(float4*)(out + (size_t)nd * 4) = r;
        }
    }
}

extern "C" void kernel_launch(void* const* d_in, const int* in_sizes, int n_in,
                              void* d_out, int out_size, void* d_ws, size_t ws_size,
                              hipStream_t stream) {
    const float* x       = (const float*)d_in[0];
    const int* ei        = (const int*)d_in[1];       // [2][EE], int32
    const float* weights = (const float*)d_in[2];
    const float* biases  = (const float*)d_in[3];
    const float* cls_w   = (const float*)d_in[4];
    const float* cls_b   = (const float*)d_in[5];
    float* out = (float*)d_out;

    char* ws = (char*)d_ws;
    size_t off = 0;
    auto alloc = [&](size_t bytes) -> void* {
        off = (off + 255) & ~(size_t)255;
        void* p = ws + off;
        off += bytes;
        return p;
    };
    int*   cnt    = (int*)alloc((size_t)NN * 4);
    int*   cursor = (int*)alloc((size_t)NN * 4);
    float* dinv   = (float*)alloc((size_t)NN * 4);
    int*   offs   = (int*)alloc((size_t)(NN + 1) * 4);
    int*   bsum   = (int*)alloc((size_t)128 * 4);
    int*   boff   = (int*)alloc((size_t)128 * 4);
    int*   col    = (int*)alloc((size_t)EE * 4);
    unsigned short* Whi = (unsigned short*)alloc((size_t)NL * FD * FD * 2);
    unsigned short* h0  = (unsigned short*)alloc((size_t)NN * FD * 2);
    unsigned short* h1  = (unsigned short*)alloc((size_t)NN * FD * 2);

    const int* srcv = ei;
    const int* dstv = ei + EE;

    hipMemsetAsync(cnt, 0, (size_t)NN * 4, stream);
    hipMemsetAsync(cursor, 0, (size_t)NN * 4, stream);
    k_deg<<<EE / 256, 256, 0, stream>>>(dstv, cnt);
    k_scanA<<<128, 256, 0, stream>>>(cnt, bsum);
    k_scanB<<<1, 128, 0, stream>>>(bsum, boff, offs);
    k_scanC<<<128, 256, 0, stream>>>(cnt, boff, offs, dinv);
    k_prep<<<EE / 256 + NL * 2048 / 256 + NN * FD / 2048, 256, 0, stream>>>(
        srcv, dstv, offs, cursor, col, weights, Whi, x, dinv, h1);  // g0 in h1

    const unsigned short* gin = h1;
    for (int l = 0; l < NL; l++) {
        unsigned short* gout = (l & 1) ? h1 : h0;
        k_layer<<<NN / MROW, 256, 0, stream>>>(gin, offs, col,
                                               Whi + (size_t)l * FD * FD,
                                               dinv, biases + (size_t)l * FD,
                                               gout, x, cls_w, cls_b, out,
                                               l == NL - 1);
        gin = gout;
    }
}